// Round 11
// baseline (251.391 us; speedup 1.0000x reference)
//
#include <hip/hip_runtime.h>
#include <math.h>

// ---------------------------------------------------------------------------
// Problem dims: B_IN=15, B1=10, B2=6, F1=20, F2=40, F_OUT=10
// M1=19, C1=9, M2=11, C2=5, batch=128
// VALID(l,m,n): |m-5|<=l && |n-5|<=l -> 286 of 726; packed base(l)=l(4l^2-1)/3
// HALF set (z2 Hermitian): dm>0 or (dm==0 && dn>=0) -> 146, l-DESCENDING.
// Parity identities (exact):
//   E_A1[mi, a+10] = (-1)^(mi-9) E_A1[mi, a]
//   E_A1[n,  g+10] = (-1)^(n-9)  E_A1[n,  g]   (g-pair fold)
//   FF2[5+d, a+10] = (-1)^d FF2[5+d, a]
//   FF2[ni,  g+10] = (-1)^(ni-5) FF2[ni, g]    (ymn g-fold)
//   E_A2[5+d, a+6] = (-1)^d E_A2[5+d, a]
//   ymn[10-mi,10-ni] = conj(ymn[mi,ni])        (y real)
// r4: __launch_bounds__(256,5) -> spills. r5/r6: occupancy pinned at 4
// blocks/CU. r8: loop-uniform table reads stay global (scalar s_load).
// r9: stage1 v17 (uniform-l WI1T). r10: stage2 v14 (depth-2 prefetch, WI2T).
// r11: stage2 v15 = v14 + (a) balanced 3rd staging slice (15 lanes/wave, was
// all-in-wave-0 -> every barrier waited on wave 0) + (b) bijective XCD
// swizzle (wg=(bid&7)*160+bid>>3): per-XCD xi footprint 5.9MB -> 0.73MB,
// L2-resident.
// ---------------------------------------------------------------------------

constexpr int OFF_WS2   = 0;                      // W_S2_FWD  [30][10][19]
constexpr int OFF_WINV1 = OFF_WS2   + 5700;       // (id range reused for WI1T)
constexpr int OFF_WSO3  = OFF_WINV1 + 72200;      // W_SO3_FWD [20][6][11][11]
constexpr int OFF_WINV2 = OFF_WSO3  + 14520;      // WI2T [12][6 mrow][11 n][8 l-pad] (6336 f)
constexpr int OFF_WINT  = OFF_WINV2 + 8712;       // W_INT     [12] (+pad)
constexpr int OFF_FE1   = OFF_WINT  + 16;         // FE1  cplx [19][30]
constexpr int OFF_EA1   = OFF_FE1   + 1140;       // E_A1 cplx [19][20]
constexpr int OFF_FF2   = OFF_EA1   + 760;        // FF2  cplx [11][20]
constexpr int OFF_EA2   = OFF_FF2   + 440;        // E_A2 cplx [11][12]
constexpr int OFF_BS2   = OFF_EA2   + 264;        // B_S2 cplx [24][10][19]
constexpr int OFF_BSO3  = OFF_BS2   + 9120;       // B_SO3 cplx[144][6][11][11] (half-set only built)
constexpr int OFF_PSI   = OFF_BSO3  + 209088;     // psi  cplx [20][10][19]
constexpr int OFF_X     = OFF_PSI   + 7600;       // X    cplx [128][10][19]
constexpr int OFF_X2P   = OFF_X     + 48640;      // X2 packed [128][20][286] cplx
constexpr int OFF_PSI2P = OFF_X2P   + 1464320;    // psi2 packed [20][40][286] cplx
constexpr int OFF_FEAT  = OFF_PSI2P + 457600;     // feat partials [128][40][4]
constexpr int OFF_VTAB  = OFF_FEAT  + 20480;      // int[286] valid (l,m,n)
constexpr int OFF_VTAB2 = OFF_VTAB  + 286;        // int[146] half-set, l desc
constexpr int OFF_ZMAP  = OFF_VTAB2 + 146;        // int[396] z2 dense rebuild map
constexpr int OFF_WI1T  = OFF_ZMAP  + 408;        // W_INV1 repack [20][10 mrow][19 ni][16 l-pad]

#define DPI 3.14159265358979323846

// ---------------------------------------------------------------------------
__device__ __forceinline__ double dpowi(double x, int n) {
    double r = 1.0;
    for (int i = 0; i < n; ++i) r *= x;
    return r;
}
// F = shared factorial table F[n] = n! (bit-identical to the former dfact loop)
__device__ double wig_d(const double* F, int l, int mi, int ni, double beta) {
    int m = mi - l, n = ni - l;
    double cb = cos(0.5 * beta), sb = sin(0.5 * beta);
    double pref = sqrt(F[l + m] * F[l - m] * F[l + n] * F[l - n]);
    int s0 = (n - m) > 0 ? (n - m) : 0;
    int s1 = (l + n) < (l - m) ? (l + n) : (l - m);
    double v = 0.0;
    for (int s = s0; s <= s1; ++s) {
        double term = dpowi(cb, 2 * l + n - m - 2 * s) * dpowi(sb, m - n + 2 * s) /
                      (F[l + n - s] * F[s] * F[m - n + s] * F[l - m - s]);
        v += ((m - n + s) & 1) ? -term : term;
    }
    return pref * v;
}
__device__ double wig_pad(const double* F, int l, int m, int n, int c, double beta) {
    if (m < c - l || m > c + l || n < c - l || n > c + l) return 0.0;
    return wig_d(F, l, m - (c - l), n - (c - l), beta);
}
__device__ double quad_w(int b, int k) {
    double beta = DPI * (2 * k + 1) / (4.0 * b);
    double s = 0.0;
    for (int j = 0; j < b; ++j) s += sin((2 * j + 1) * beta) / (double)(2 * j + 1);
    return 2.0 / b * sin(beta) * s;
}

// element ids total = 212378 (unread entries skipped)
__global__ __launch_bounds__(256) void build_tables_kernel(float* ws) {
    __shared__ double sfact[21];
    if (threadIdx.x == 0) {
        double f = 1.0;
        sfact[0] = 1.0;
        for (int i = 1; i <= 20; ++i) { f *= (double)i; sfact[i] = f; }
    }
    __syncthreads();
    const double* F = sfact;

    int idx = blockIdx.x * 256 + threadIdx.x;
    if (idx < 5700) {
        int k = idx / 190, r = idx % 190, l = r / 19, m = r % 19;
        double beta = DPI * (2 * k + 1) / 60.0;
        ws[OFF_WS2 + idx] = (float)(quad_w(15, k) * wig_pad(F, l, m, 9, 9, beta));
        return;
    }
    idx -= 5700;
    if (idx < 72200) {
        // WI1T [k][mrow][ni][l] l-contiguous, pad 16; all l in [0,10) written
        if (idx >= 38000) return;
        int l = idx % 10, r = idx / 10;
        int ni = r % 19, r2 = r / 19;
        int mrow = r2 % 10, k = r2 / 10;
        double beta = DPI * (2 * k + 1) / 40.0;
        ws[OFF_WI1T + ((k * 10 + mrow) * 19 + ni) * 16 + l] =
            (float)((2 * l + 1) * wig_pad(F, l, mrow + 9, ni, 9, beta));
        return;
    }
    idx -= 72200;
    if (idx < 14520) {
        int k = idx / 726, r = idx % 726, l = r / 121, m = (r % 121) / 11, n = r % 11;
        double beta = DPI * (2 * k + 1) / 40.0;
        ws[OFF_WSO3 + idx] = (float)(quad_w(10, k) * wig_pad(F, l, m, n, 5, beta));
        return;
    }
    idx -= 14520;
    if (idx < 8712) {
        // WI2T [k2][mrow(m-5)][n][l] l-contiguous, pad 8; l>=6 pad = 0
        if (idx >= 6336) return;
        int l = idx & 7, r = idx >> 3;
        int n = r % 11, r2 = r / 11;
        int mrow = r2 % 6, k2 = r2 / 6;
        double beta = DPI * (2 * k2 + 1) / 24.0;
        float v = 0.f;
        if (l < 6) v = (float)((2 * l + 1) * wig_pad(F, l, mrow + 5, n, 5, beta));
        ws[OFF_WINV2 + ((k2 * 6 + mrow) * 11 + n) * 8 + l] = v;
        return;
    }
    idx -= 8712;
    if (idx < 12) { ws[OFF_WINT + idx] = (float)quad_w(6, idx); return; }
    idx -= 12;
    if (idx < 570) {
        int m = idx / 30, t = idx % 30;
        double ang = -2.0 * DPI * (double)((m - 9) * t) / 30.0;
        ws[OFF_FE1 + 2 * idx] = (float)cos(ang);
        ws[OFF_FE1 + 2 * idx + 1] = (float)sin(ang);
        return;
    }
    idx -= 570;
    if (idx < 380) {
        int m = idx / 20, a = idx % 20;
        double ang = 2.0 * DPI * (double)((m - 9) * a) / 20.0;
        ws[OFF_EA1 + 2 * idx] = (float)cos(ang);
        ws[OFF_EA1 + 2 * idx + 1] = (float)sin(ang);
        return;
    }
    idx -= 380;
    if (idx < 220) {
        int m = idx / 20, a = idx % 20;
        double ang = -2.0 * DPI * (double)((m - 5) * a) / 20.0;
        ws[OFF_FF2 + 2 * idx] = (float)cos(ang);
        ws[OFF_FF2 + 2 * idx + 1] = (float)sin(ang);
        return;
    }
    idx -= 220;
    if (idx < 132) {
        int m = idx / 12, a = idx % 12;
        double ang = 2.0 * DPI * (double)((m - 5) * a) / 12.0;
        ws[OFF_EA2 + 2 * idx] = (float)cos(ang);
        ws[OFF_EA2 + 2 * idx + 1] = (float)sin(ang);
        return;
    }
    idx -= 132;
    if (idx < 4560) {
        int p = idx / 190, r = idx % 190, l = r / 19, m = r % 19;
        int bi = p / 8, ai = p % 8;
        double beta = (bi + 1) * (DPI / 24.0);
        double alpha = 2.0 * DPI * ai / 8.0;
        double re = 0.0, im = 0.0;
        if (m - 9 >= -l && m - 9 <= l) {
            double d = wig_d(F, l, m - 9 + l, l, beta);
            double ang = -(double)(m - 9) * alpha;
            re = d * cos(ang); im = d * sin(ang);
        }
        ws[OFF_BS2 + 2 * idx] = (float)re;
        ws[OFF_BS2 + 2 * idx + 1] = (float)im;
        return;
    }
    idx -= 4560;
    if (idx < 104544) {
        int p = idx / 726, r = idx % 726, l = r / 121, m = (r % 121) / 11, n = r % 11;
        int dm = m - 5, dn = n - 5;
        int am = dm < 0 ? -dm : dm, an = dn < 0 ? -dn : dn;
        if (am > l || an > l) return;                       // structurally zero
        if (!((dm > 0) || (dm == 0 && dn >= 0))) return;    // psi2 reads half-set only
        int bi = p / 48, ai = (p % 48) / 6, gi = p % 6;
        double beta = (bi + 1) * (DPI / 24.0);
        double alpha = 2.0 * DPI * ai / 8.0;
        double gamma = 2.0 * DPI * gi / 6.0;
        double d = wig_d(F, l, m - 5 + l, n - 5 + l, beta);
        double ang = -((double)(m - 5) * alpha + (double)(n - 5) * gamma);
        ws[OFF_BSO3 + 2 * idx] = (float)(d * cos(ang));
        ws[OFF_BSO3 + 2 * idx + 1] = (float)(d * sin(ang));
        return;
    }
    idx -= 104544;
    if (idx < 286) {
        int l = 0, cum = 0;
        while (idx >= cum + (2 * l + 1) * (2 * l + 1)) { cum += (2 * l + 1) * (2 * l + 1); ++l; }
        int rem = idx - cum, w = 2 * l + 1;
        int m = 5 - l + rem / w, n = 5 - l + rem % w;
        ((int*)(ws + OFF_VTAB))[idx] = l | (m << 4) | (n << 8);
        return;
    }
    idx -= 286;
    if (idx < 146) {
        int l = 5, st = 0;
        while (idx >= st + (2 * l * l + 2 * l + 1)) { st += 2 * l * l + 2 * l + 1; --l; }
        int rem = idx - st;
        int dm, dn;
        if (rem < l + 1) { dm = 0; dn = rem; }
        else { int r2 = rem - (l + 1); dm = 1 + r2 / (2 * l + 1); dn = r2 % (2 * l + 1) - l; }
        ((int*)(ws + OFF_VTAB2))[idx] = l | ((dm + 5) << 4) | ((dn + 5) << 8);
        return;
    }
    idx -= 146;
    if (idx < 396) {
        // dense z2 rebuild map: idx = ll*66 + dm*11 + n  ->  h | conj<<8 | neg<<9, -1 if zero
        int ll = idx / 66, rr = idx - ll * 66, dm = rr / 11, n = rr - dm * 11;
        int dn = n - 5, an = dn < 0 ? -dn : dn;
        int zv = -1;
        if (dm <= ll && an <= ll) {
            bool inhalf = (dm > 0) || (dm == 0 && dn >= 0);
            int ddm = inhalf ? dm : -dm, ddn = inhalf ? dn : -dn;
            int lp = ll + 1;
            int st = 146 - lp * (2 * lp * lp + 1) / 3;
            int h = st + (ddm == 0 ? ddn : (ll + 1) + (ddm - 1) * (2 * ll + 1) + (ddn + ll));
            zv = h;
            if (!inhalf) zv |= 256 | ((((dm + an) & 1) ? 1 : 0) << 9);
        }
        ((int*)(ws + OFF_ZMAP))[idx] = zv;
        return;
    }
}

// ---------------------------------------------------------------------------
// prep_kernel: psi2 (blocks 0..456) + xform1 (457..584) + psi1 (585..599)
// ---------------------------------------------------------------------------
__global__ __launch_bounds__(256) void prep_kernel(float* ws,
                                                   const float* __restrict__ k1,
                                                   const float* __restrict__ k2,
                                                   const float* __restrict__ x) {
    const int bid = blockIdx.x, tid = threadIdx.x;
    __shared__ float xs[900];
    __shared__ float2 xm[570];

    if (bid < 457) {
        int idx = bid * 256 + tid;
        if (idx >= 116800) return;
        int i = idx / 5840, r = idx % 5840, o = r / 146, h = r % 146;
        int w = ((const int*)(ws + OFF_VTAB2))[h];
        int l = w & 15, dm = ((w >> 4) & 15) - 5, dn = ((w >> 8) & 15) - 5;
        int lmn = l * 121 + (dm + 5) * 11 + (dn + 5);
        const float2* BS = (const float2*)(ws + OFF_BSO3);
        float2 s = {0.f, 0.f};
        for (int p = 0; p < 144; ++p) {
            float wv = k2[(i * 40 + o) * 144 + p];
            float2 bv = BS[p * 726 + lmn];
            s.x += wv * bv.x; s.y += wv * bv.y;
        }
        float2* row = (float2*)(ws + OFF_PSI2P) + (i * 40 + o) * 286;
        int base = l * (4 * l * l - 1) / 3, span = 2 * l + 1;
        row[base + (dm + l) * span + (dn + l)] = s;
        float sign = ((dm + dn + 16) & 1) ? -1.f : 1.f;
        row[base + (-dm + l) * span + (-dn + l)] = make_float2(sign * s.x, -sign * s.y);
        return;
    }
    if (bid < 585) {
        const int b = bid - 457;
        const float2* FE1 = (const float2*)(ws + OFF_FE1);
        const float* WS2 = ws + OFF_WS2;
        float2* Xg = (float2*)(ws + OFF_X) + b * 190;
        for (int i = tid; i < 900; i += 256) xs[i] = x[b * 900 + i];
        __syncthreads();
        for (int i = tid; i < 570; i += 256) {
            int k = i / 19, m = i % 19;
            float2 s = {0.f, 0.f};
            #pragma unroll
            for (int t = 0; t < 30; ++t) {
                float v = xs[k * 30 + t];
                float2 e = FE1[m * 30 + t];
                s.x += v * e.x; s.y += v * e.y;
            }
            xm[k * 19 + m] = s;
        }
        __syncthreads();
        for (int i = tid; i < 190; i += 256) {
            int l = i / 19, m = i % 19;
            float2 s = {0.f, 0.f};
            for (int k = 0; k < 30; ++k) {
                float w = WS2[k * 190 + l * 19 + m];
                float2 v = xm[k * 19 + m];
                s.x += w * v.x; s.y += w * v.y;
            }
            Xg[i] = s;
        }
        return;
    }
    {
        int idx = (bid - 585) * 256 + tid;
        if (idx >= 3800) return;
        int o = idx / 190, r = idx % 190;
        const float2* BS2 = (const float2*)(ws + OFF_BS2);
        float2 s = {0.f, 0.f};
        for (int p = 0; p < 24; ++p) {
            float w = k1[o * 24 + p];
            float2 bv = BS2[p * 190 + r];
            s.x += w * bv.x; s.y += w * bv.y;
        }
        ((float2*)(ws + OFF_PSI))[idx] = s;
    }
}

// ---------------------------------------------------------------------------
// stage1 v17 (r9-validated): per-wave k-ownership, 2 barriers, global EA1/FF2
// (scalar s_loads), uniform l=0..9 + l-contiguous WI1T dwordx4 loads.
// ---------------------------------------------------------------------------
__global__ __launch_bounds__(256, 4) void stage1_kernel(
    const float* __restrict__ WI1T, const float* __restrict__ WS3,
    const float* __restrict__ EA1, const float* __restrict__ FF2,
    const float2* __restrict__ Xall, const float2* __restrict__ Pall,
    const int* __restrict__ VTAB, float2* __restrict__ X2out)
{
    const int tid = threadIdx.x;
    const int wv = tid >> 6, lane = tid & 63;
    const int b = blockIdx.x / 20;
    const int o = blockIdx.x % 20;
    const float2* Xg = Xall + b * 190;
    const float2* Pg = Pall + o * 190;
    float2* X2g = X2out + (b * 20 + o) * 286;
    const float2* EA1c = (const float2*)EA1;
    const float2* FF2c = (const float2*)FF2;

    __shared__ float2 Xs[100];         // [l][mrow] = X[l][mrow+9], dense
    __shared__ float2 Ps[190];         // [l][ni], dense
    __shared__ float2 fhA[3800];       // [20 k][190]; uu aliases [950w,950w+600),
                                       // ymn rows k at [950*(k/5)+600+(k%5)*66, +66)

    const int kl = lane / 10;          // local k within wave (active: kl < 5)
    const int gpair = lane % 10;
    const bool active = (lane < 50);

    float2 eg[19];
    #pragma unroll
    for (int n = 0; n < 19; ++n) eg[n] = EA1c[n * 20 + gpair];

    // wave-redundant staging (identical values -> benign WW race, no barrier)
    for (int i = lane; i < 100; i += 64) Xs[i] = Xg[(i / 10) * 19 + 9 + (i % 10)];
    for (int i = lane; i < 190; i += 64) Ps[i] = Pg[i];

    // (a) wave-local: build own 5 fh rows (950 items), uniform l=0..9
    float2* fhW = fhA + 950 * wv;
    for (int i = lane; i < 950; i += 64) {
        int klq = i / 190, idx = i - klq * 190;
        int k = 5 * wv + klq;
        int mrow = idx / 19, ni = idx - mrow * 19;
        const float* wt = WI1T + ((k * 10 + mrow) * 19 + ni) * 16;
        float4 wa = *(const float4*)(wt);
        float4 wb = *(const float4*)(wt + 4);
        float2 wc = *(const float2*)(wt + 8);
        float wl_[10] = {wa.x, wa.y, wa.z, wa.w, wb.x, wb.y, wb.z, wb.w, wc.x, wc.y};
        float2 s = {0.f, 0.f};
        #pragma unroll
        for (int l = 0; l < 10; ++l) {
            float2 a = Xs[l * 10 + mrow], c = Ps[l * 19 + ni];
            float wvv = wl_[l];
            s.x += wvv * (a.x * c.x + a.y * c.y);
            s.y += wvv * (a.y * c.x - a.x * c.y);
        }
        fhW[i] = s;
    }

    // (b) wave-local per-lane column-PAIR pipeline (reads own rows only)
    float2 uacc0[6], uacc1[6];
    if (active) {
        const float2* fhk = fhW + kl * 190;
        float ye0[10], yo0[10], ye1[10], yo1[10];
        {
            float2 te = {0.f, 0.f}, to = {0.f, 0.f};
            #pragma unroll
            for (int n = 0; n < 19; ++n) {
                float2 f = fhk[n];
                float rx = f.x * eg[n].x - f.y * eg[n].y;
                float ry = f.x * eg[n].y + f.y * eg[n].x;
                if (n & 1) { te.x += rx; te.y += ry; }
                else       { to.x += rx; to.y += ry; }
            }
            float t0x = te.x + to.x, t1x = te.x - to.x;
            #pragma unroll
            for (int a = 0; a < 10; ++a) {
                ye0[a] = t0x; yo0[a] = 0.f;
                ye1[a] = t1x; yo1[a] = 0.f;
            }
        }
        #pragma unroll 1   // r7 lesson: full unroll -> VGPR cliff
        for (int mrow = 1; mrow < 10; ++mrow) {
            float2 te = {0.f, 0.f}, to = {0.f, 0.f};
            #pragma unroll
            for (int n = 0; n < 19; ++n) {
                float2 f = fhk[mrow * 19 + n];
                float rx = f.x * eg[n].x - f.y * eg[n].y;
                float ry = f.x * eg[n].y + f.y * eg[n].x;
                if (n & 1) { te.x += rx; te.y += ry; }
                else       { to.x += rx; to.y += ry; }
            }
            float2 t0 = make_float2(2.f * (te.x + to.x), 2.f * (te.y + to.y));
            float2 t1 = make_float2(2.f * (te.x - to.x), 2.f * (te.y - to.y));
            if (mrow & 1) {
                #pragma unroll
                for (int a = 0; a < 10; ++a) {
                    float2 e = EA1c[(9 + mrow) * 20 + a];
                    yo0[a] += t0.x * e.x - t0.y * e.y;
                    yo1[a] += t1.x * e.x - t1.y * e.y;
                }
            } else {
                #pragma unroll
                for (int a = 0; a < 10; ++a) {
                    float2 e = EA1c[(9 + mrow) * 20 + a];
                    ye0[a] += t0.x * e.x - t0.y * e.y;
                    ye1[a] += t1.x * e.x - t1.y * e.y;
                }
            }
        }
        #pragma unroll
        for (int a = 0; a < 10; ++a) {
            float p0 = ye0[a] + yo0[a]; p0 = p0 > 0.f ? p0 : 0.f;
            float q0 = ye0[a] - yo0[a]; q0 = q0 > 0.f ? q0 : 0.f;
            ye0[a] = p0 + q0; yo0[a] = p0 - q0;
            float p1 = ye1[a] + yo1[a]; p1 = p1 > 0.f ? p1 : 0.f;
            float q1 = ye1[a] - yo1[a]; q1 = q1 > 0.f ? q1 : 0.f;
            ye1[a] = p1 + q1; yo1[a] = p1 - q1;
        }
        uacc0[0] = make_float2(0.f, 0.f); uacc1[0] = make_float2(0.f, 0.f);
        #pragma unroll
        for (int a = 0; a < 10; ++a) { uacc0[0].x += ye0[a]; uacc1[0].x += ye1[a]; }
        #pragma unroll
        for (int d = 1; d < 6; ++d) {
            uacc0[d] = make_float2(0.f, 0.f); uacc1[d] = make_float2(0.f, 0.f);
            #pragma unroll
            for (int a = 0; a < 10; ++a) {
                float q0 = (d & 1) ? yo0[a] : ye0[a];
                float q1 = (d & 1) ? yo1[a] : ye1[a];
                float2 e = FF2c[(5 + d) * 20 + a];
                uacc0[d].x += e.x * q0; uacc0[d].y += e.y * q0;
                uacc1[d].x += e.x * q1; uacc1[d].y += e.y * q1;
            }
        }
    }

    // (c) wave-local uu write into own (already-consumed) region
    if (active) {
        float2* uu = fhW + kl * 120;
        #pragma unroll
        for (int d = 0; d < 6; ++d) {
            uu[d * 20 + gpair]      = uacc0[d];
            uu[d * 20 + gpair + 10] = uacc1[d];
        }
    }
    __syncthreads();   // barrier #1: all waves' uu visible

    // (d) block-wide: ymn rows mi=5..10, g-FOLDED; writes into per-wave gaps
    for (int i = tid; i < 1320; i += 256) {
        int k = i / 66, rr = i - k * 66;
        int d = rr / 11, ni = rr - d * 11;
        const float2* uurow = fhA + 950 * (k / 5) + (k % 5) * 120 + d * 20;
        float sgn = (ni & 1) ? 1.f : -1.f;
        float2 s = {0.f, 0.f};
        #pragma unroll
        for (int gg = 0; gg < 10; ++gg) {
            float2 ua = uurow[gg], ub = uurow[gg + 10];
            float ux = ua.x + sgn * ub.x, uy = ua.y + sgn * ub.y;
            float2 e = FF2c[ni * 20 + gg];
            s.x += ux * e.x - uy * e.y;
            s.y += ux * e.y + uy * e.x;
        }
        fhA[950 * (k / 5) + 600 + (k % 5) * 66 + rr] = s;
    }
    __syncthreads();   // barrier #2: ymn visible

    // (e) per-lane acc over all 20 k + packed write
    for (int v = tid; v < 286; v += 256) {
        int w = VTAB[v];
        int l = w & 15, m = (w >> 4) & 15, n = (w >> 8) & 15;
        int fidx = l * 121 + m * 11 + n;
        int off; float sy;
        if (m >= 5) { off = (m - 5) * 11 + n; sy = 1.f; }
        else        { off = (5 - m) * 11 + (10 - n); sy = -1.f; }
        float2 s = {0.f, 0.f};
        for (int k = 0; k < 20; ++k) {
            float wvv = WS3[k * 726 + fidx];
            float2 ym = fhA[950 * (k / 5) + 600 + (k % 5) * 66 + off];
            s.x += wvv * ym.x;
            s.y += wvv * sy * ym.y;
        }
        X2g[v] = s;
    }
}

// ---------------------------------------------------------------------------
// stage2 v15 = v14 + balanced 3rd staging slice (15 lanes/wave instead of
// all-60-in-wave-0: wave 0 was the straggler at every phase-A barrier) +
// bijective XCD swizzle (1280 = 8x160; each XCD covers bp in [8x,8x+8) x all
// og -> per-XCD xi footprint 0.73MB, L2-resident). Arithmetic per (b,o)
// unchanged -> bit-identical output.
// ---------------------------------------------------------------------------
__global__ __launch_bounds__(256) void stage2_kernel(float* ws) {
    const int tid = threadIdx.x;
    const int wave = tid >> 6, lane = tid & 63;
    // XCD-aware bijective remap: blockIdx round-robins XCDs; give each XCD a
    // contiguous chunk of (bp,og) space so same-bp blocks share an L2.
    const int wg = (blockIdx.x & 7) * 160 + (blockIdx.x >> 3);
    const int bp = wg / 20;                    // b-pair 0..63
    const int og = wg % 20;                    // o-pair 0..19
    const int b0 = bp * 2, o0 = og * 2;
    const int bsel = wave >> 1, osel = wave & 1;   // wave w -> (b0+bsel, o0+osel)

    const float*  WI2T = ws + OFF_WINV2;   // [k2][mrow][n][8 l-pad]
    const float2* EA2 = (const float2*)(ws + OFF_EA2);
    const float*  WIT = ws + OFF_WINT;
    const int*  VTAB2 = (const int*)(ws + OFF_VTAB2);
    const int*   ZMAP = (const int*)(ws + OFF_ZMAP);
    const float4* WS4 = (const float4*)ws;
    float* featp = ws + OFF_FEAT;

    // LDS (floats): [0,1168) P partials [4 pair][146] f2 (live past phase A)
    //   [1168,5808): staging dbuf, 2 x 2320 f (4 arrays @ f2 0/286/572/858,
    //                pad f2 1144..1160 for masked unroll reads)
    //   B/C alias: z2a [1168,1960) 396 f2 ; z2b [1960,2752) 396 f2
    //              fh2 [2752,4336) 792 f2 ; t2 [4336,6064) 864 f2
    __shared__ __align__(16) float sm[6064];

    // per-lane entry setup (same half-set per wave; wave's own (b,o) pair)
    int xo[3], po[3], klen[3];
    float2 acc[3];
    #pragma unroll
    for (int t = 0; t < 3; ++t) {
        int v = lane + 64 * t;
        acc[t] = make_float2(0.f, 0.f);
        if (v < 146) {
            int w = VTAB2[v];
            int l = w & 15, dm = ((w >> 4) & 15) - 5, dn = ((w >> 8) & 15) - 5;
            int base = l * (4 * l * l - 1) / 3, span = 2 * l + 1;
            xo[t] = base + (dm + l) * span;
            po[t] = base + (dn + l) * span;
            klen[t] = span;
        } else { xo[t] = 0; po[t] = 0; klen[t] = 0; }
    }

    // staging source setup: arrays [xi(b0), xi(b0+1), pp(o0), pp(o0+1)],
    // each 143 float4; 572 f4 per tile. Slices 0/1: v = tid, tid+256.
    // Slice 2 (60 items): v = 512 + wave*15 + lane, lane<15 — balanced
    // across waves (was tid<60 = all wave 0 -> barrier straggler).
    int fb[3], fstep[3];
    #pragma unroll
    for (int j = 0; j < 2; ++j) {
        int v = tid + 256 * j;
        int arr = v / 143, idxq = v - arr * 143;
        if (arr < 2) { fb[j] = (OFF_X2P >> 2) + (b0 + arr) * 20 * 143 + idxq; fstep[j] = 143; }
        else         { fb[j] = (OFF_PSI2P >> 2) + (o0 + arr - 2) * 143 + idxq; fstep[j] = 5720; }
    }
    int e3 = wave * 15 + lane; if (e3 > 59) e3 = 59;
    const int v3 = 512 + e3;                 // in [512,571] -> arr==3 always
    fb[2] = (OFF_PSI2P >> 2) + (o0 + 1) * 143 + (v3 - 429);
    fstep[2] = 5720;
    const bool f2ok = (lane < 15);

    constexpr int KMAX0 = 11, KMAX1 = 9, KMAX2 = 5;   // static slot max klen
    auto computeTile = [&](const float* smbase) {
        const float2* bufF2 = (const float2*)smbase;
        const float2* xiW = bufF2 + bsel * 286;
        const float2* ppW = bufF2 + (2 + osel) * 286;
        {
            const float2* xp = xiW + xo[0];
            const float2* pq = ppW + po[0];
            const int kl = klen[0];
            #pragma unroll
            for (int k = 0; k < KMAX0; ++k) {
                float2 u = xp[k], v2 = pq[k];
                if (k < kl) {
                    acc[0].x += u.x * v2.x + u.y * v2.y;
                    acc[0].y += u.y * v2.x - u.x * v2.y;
                }
            }
        }
        {
            const float2* xp = xiW + xo[1];
            const float2* pq = ppW + po[1];
            const int kl = klen[1];
            #pragma unroll
            for (int k = 0; k < KMAX1; ++k) {
                float2 u = xp[k], v2 = pq[k];
                if (k < kl) {
                    acc[1].x += u.x * v2.x + u.y * v2.y;
                    acc[1].y += u.y * v2.x - u.x * v2.y;
                }
            }
        }
        {
            const float2* xp = xiW + xo[2];
            const float2* pq = ppW + po[2];
            const int kl = klen[2];
            #pragma unroll
            for (int k = 0; k < KMAX2; ++k) {
                float2 u = xp[k], v2 = pq[k];
                if (k < kl) {
                    acc[2].x += u.x * v2.x + u.y * v2.y;
                    acc[2].y += u.y * v2.x - u.x * v2.y;
                }
            }
        }
    };

    // prefetch tiles 0 (set A) and 1 (set B)
    float4 rgA0 = WS4[fb[0]], rgA1 = WS4[fb[1]];
    float4 rgA2; if (f2ok) rgA2 = WS4[fb[2]];
    fb[0] += fstep[0]; fb[1] += fstep[1]; fb[2] += fstep[2];
    float4 rgB0 = WS4[fb[0]], rgB1 = WS4[fb[1]];
    float4 rgB2; if (f2ok) rgB2 = WS4[fb[2]];

    // phase A: unroll-by-2, 1 barrier/half-iter, loads issued 2 tiles ahead
    for (int i = 0; i < 20; i += 2) {
        float4* A4 = (float4*)(sm + 1168);
        A4[tid]       = rgA0;
        A4[tid + 256] = rgA1;
        if (f2ok) A4[v3] = rgA2;
        __syncthreads();
        if (i + 2 < 20) {
            fb[0] += fstep[0]; fb[1] += fstep[1]; fb[2] += fstep[2];
            rgA0 = WS4[fb[0]]; rgA1 = WS4[fb[1]];
            if (f2ok) rgA2 = WS4[fb[2]];
        }
        computeTile(sm + 1168);

        float4* B4 = (float4*)(sm + 1168 + 2320);
        B4[tid]       = rgB0;
        B4[tid + 256] = rgB1;
        if (f2ok) B4[v3] = rgB2;
        __syncthreads();
        if (i + 3 < 20) {
            fb[0] += fstep[0]; fb[1] += fstep[1]; fb[2] += fstep[2];
            rgB0 = WS4[fb[0]]; rgB1 = WS4[fb[1]];
            if (f2ok) rgB2 = WS4[fb[2]];
        }
        computeTile(sm + 1168 + 2320);
    }

    // write complete per-pair partials (P region disjoint from staging)
    float2* P = (float2*)sm;   // [4 pair][146]
    #pragma unroll
    for (int t = 0; t < 3; ++t) {
        int v = lane + 64 * t;
        if (v < 146) P[wave * 146 + v] = acc[t];
    }
    __syncthreads();

    // phases B/C per pair p: (b0 + (p>>1), o0 + (p&1)); z2 double-buffered,
    // z2(p+1) built between fh2(p) and t2(p) -> one barrier per pair.
    float2* z2A = (float2*)(sm + 1168);   // [6 l][6 m>=5][11 n]
    float2* z2B = (float2*)(sm + 1960);
    float2* fh2 = (float2*)(sm + 2752);   // [12 k2][6 m][11 n]
    float2* t2  = (float2*)(sm + 4336);   // [12 k2][6 d][12 g]

    // prologue: build z2 for p=0
    for (int idx = tid; idx < 396; idx += 256) {
        int zv = ZMAP[idx];
        float2 s = {0.f, 0.f};
        if (zv >= 0) {
            s = P[(zv & 255)];
            if (zv & 256) {
                float sg = (zv & 512) ? -1.f : 1.f;
                s = make_float2(sg * s.x, -sg * s.y);
            }
        }
        z2A[idx] = s;
    }
    __syncthreads();

    for (int p = 0; p < 4; ++p) {
        const float2* zin  = (p & 1) ? z2B : z2A;
        float2*       zout = (p & 1) ? z2A : z2B;
        // C: fh2 rows for own k2 = 3w..3w+2 (198 items/wave), uniform ll=0..5
        for (int li = lane; li < 198; li += 64) {
            int k2 = wave * 3 + li / 66;
            int rr = li % 66;
            const float* wt = WI2T + (k2 * 66 + rr) * 8;
            float4 wa = *(const float4*)(wt);
            float2 wb = *(const float2*)(wt + 4);
            float wl_[6] = {wa.x, wa.y, wa.z, wa.w, wb.x, wb.y};
            float2 s = {0.f, 0.f};
            #pragma unroll
            for (int ll = 0; ll < 6; ++ll) {
                float2 z = zin[ll * 66 + rr];
                s.x += wl_[ll] * z.x; s.y += wl_[ll] * z.y;
            }
            fh2[k2 * 66 + rr] = s;
        }
        asm volatile("s_waitcnt lgkmcnt(0)" ::: "memory");   // wave-local fh2 ready
        // pipeline: build z2 for next pair into the other buffer (block-wide;
        // completion guaranteed by the end-of-pair barrier)
        if (p < 3) {
            for (int idx = tid; idx < 396; idx += 256) {
                int zv = ZMAP[idx];
                float2 s = {0.f, 0.f};
                if (zv >= 0) {
                    s = P[(p + 1) * 146 + (zv & 255)];
                    if (zv & 256) {
                        float sg = (zv & 512) ? -1.f : 1.f;
                        s = make_float2(sg * s.x, -sg * s.y);
                    }
                }
                zout[idx] = s;
            }
        }
        // t2: per-wave own k2 (216 items/wave)
        for (int li = lane; li < 216; li += 64) {
            int k2 = wave * 3 + li / 72;
            int rr = li % 72, mrow = rr / 12, g = rr - mrow * 12;
            float2 s = {0.f, 0.f};
            #pragma unroll
            for (int n = 0; n < 11; ++n) {
                float2 f = fh2[k2 * 66 + mrow * 11 + n], e = EA2[n * 12 + g];
                s.x += f.x * e.x - f.y * e.y;
                s.y += f.x * e.y + f.y * e.x;
            }
            t2[k2 * 72 + rr] = s;
        }
        asm volatile("s_waitcnt lgkmcnt(0)" ::: "memory");   // wave-local t2 ready
        // final: per-wave own k2 (216 items/wave), relu + quad-weight acc
        float partial = 0.f;
        for (int li = lane; li < 216; li += 64) {
            int k2 = wave * 3 + li / 72;
            int rr = li % 72, a = rr / 12, g = rr - a * 12;
            float base = t2[k2 * 72 + g].x;
            float se = 0.f, so = 0.f;
            #pragma unroll
            for (int d = 1; d < 6; ++d) {
                float2 e = EA2[(5 + d) * 12 + a];
                float2 t = t2[k2 * 72 + d * 12 + g];
                float c = 2.f * (e.x * t.x - e.y * t.y);
                if (d & 1) so += c; else se += c;
            }
            float y0 = base + se + so, y1 = base + se - so;
            float w = WIT[k2];
            if (y0 > 0.f) partial += w * y0;
            if (y1 > 0.f) partial += w * y1;
        }
        for (int off = 32; off > 0; off >>= 1) partial += __shfl_down(partial, off, 64);
        if (lane == 0)
            featp[((b0 + (p >> 1)) * 40 + o0 + (p & 1)) * 4 + wave] = partial;
        __syncthreads();   // z2(p+1) complete; safe to reuse buffers next pair
    }
}

// ---------------------------------------------------------------------------
__global__ __launch_bounds__(256) void final_kernel(const float* __restrict__ ws,
                                                    const float* __restrict__ wl,
                                                    const float* __restrict__ bl,
                                                    float* __restrict__ out) {
    int idx = blockIdx.x * 256 + threadIdx.x;
    if (idx >= 1280) return;
    int b = idx / 10, f = idx % 10;
    const float* fp = ws + OFF_FEAT;
    float s = bl[f];
    for (int o = 0; o < 40; ++o) {
        const float* q = fp + (b * 40 + o) * 4;
        s += ((q[0] + q[1] + q[2] + q[3]) * (1.0f / 144.0f)) * wl[f * 40 + o];
    }
    out[idx] = s;
}

// ---------------------------------------------------------------------------
extern "C" void kernel_launch(void* const* d_in, const int* in_sizes, int n_in,
                              void* d_out, int out_size, void* d_ws, size_t ws_size,
                              hipStream_t stream) {
    (void)in_sizes; (void)n_in; (void)out_size; (void)ws_size;
    const float* x  = (const float*)d_in[0];
    const float* k1 = (const float*)d_in[1];
    const float* k2 = (const float*)d_in[2];
    const float* wl = (const float*)d_in[3];
    const float* bl = (const float*)d_in[4];
    float* out = (float*)d_out;
    float* ws  = (float*)d_ws;

    build_tables_kernel<<<830, 256, 0, stream>>>(ws);
    prep_kernel<<<600, 256, 0, stream>>>(ws, k1, k2, x);
    stage1_kernel<<<128 * 20, 256, 0, stream>>>(
        ws + OFF_WI1T, ws + OFF_WSO3, ws + OFF_EA1, ws + OFF_FF2,
        (const float2*)(ws + OFF_X), (const float2*)(ws + OFF_PSI),
        (const int*)(ws + OFF_VTAB), (float2*)(ws + OFF_X2P));
    stage2_kernel<<<128 * 10, 256, 0, stream>>>(ws);
    final_kernel<<<5, 256, 0, stream>>>(ws, wl, bl, out);
}

// Round 12
// 243.861 us; speedup vs baseline: 1.0309x; 1.0309x over previous
//
#include <hip/hip_runtime.h>
#include <math.h>

// ---------------------------------------------------------------------------
// Problem dims: B_IN=15, B1=10, B2=6, F1=20, F2=40, F_OUT=10
// M1=19, C1=9, M2=11, C2=5, batch=128
// VALID(l,m,n): |m-5|<=l && |n-5|<=l -> 286 of 726; packed base(l)=l(4l^2-1)/3
// HALF set (z2 Hermitian): dm>0 or (dm==0 && dn>=0) -> 146, l-DESCENDING.
// Parity identities (exact):
//   E_A1[mi, a+10] = (-1)^(mi-9) E_A1[mi, a]
//   E_A1[n,  g+10] = (-1)^(n-9)  E_A1[n,  g]   (g-pair fold)
//   FF2[5+d, a+10] = (-1)^d FF2[5+d, a]
//   FF2[ni,  g+10] = (-1)^(ni-5) FF2[ni, g]    (ymn g-fold)
//   E_A2[5+d, a+6] = (-1)^d E_A2[5+d, a]
//   ymn[10-mi,10-ni] = conj(ymn[mi,ni])        (y real)
// r4: __launch_bounds__(256,5) -> spills. r5/r6: occupancy pinned at 4
// blocks/CU. r8: loop-UNIFORM table reads stay global (scalar s_load);
// per-lane-varying reads are vector gathers and DO benefit from LDS.
// r9/r10: k-strided scalar gathers -> contiguous dwordx4 (WI1T, WI2T).
// r11: balanced staging slice + bijective XCD swizzle (FETCH 24.9->10.2MB).
// r12: same repack pattern a 3rd time: WS3T[fidx][20] for stage1 (e);
// EA2 staged in LDS for stage2 t2/final (per-lane g/a gathers).
// ---------------------------------------------------------------------------

constexpr int OFF_WS2   = 0;                      // W_S2_FWD  [30][10][19]
constexpr int OFF_WINV1 = OFF_WS2   + 5700;       // (id range reused for WI1T)
constexpr int OFF_WSO3  = OFF_WINV1 + 72200;      // WS3T [726 fidx][20 k] k-contiguous
constexpr int OFF_WINV2 = OFF_WSO3  + 14520;      // WI2T [12][6 mrow][11 n][8 l-pad] (6336 f)
constexpr int OFF_WINT  = OFF_WINV2 + 8712;       // W_INT     [12] (+pad)
constexpr int OFF_FE1   = OFF_WINT  + 16;         // FE1  cplx [19][30]
constexpr int OFF_EA1   = OFF_FE1   + 1140;       // E_A1 cplx [19][20]
constexpr int OFF_FF2   = OFF_EA1   + 760;        // FF2  cplx [11][20]
constexpr int OFF_EA2   = OFF_FF2   + 440;        // E_A2 cplx [11][12]
constexpr int OFF_BS2   = OFF_EA2   + 264;        // B_S2 cplx [24][10][19]
constexpr int OFF_BSO3  = OFF_BS2   + 9120;       // B_SO3 cplx[144][6][11][11] (half-set only built)
constexpr int OFF_PSI   = OFF_BSO3  + 209088;     // psi  cplx [20][10][19]
constexpr int OFF_X     = OFF_PSI   + 7600;       // X    cplx [128][10][19]
constexpr int OFF_X2P   = OFF_X     + 48640;      // X2 packed [128][20][286] cplx
constexpr int OFF_PSI2P = OFF_X2P   + 1464320;    // psi2 packed [20][40][286] cplx
constexpr int OFF_FEAT  = OFF_PSI2P + 457600;     // feat partials [128][40][4]
constexpr int OFF_VTAB  = OFF_FEAT  + 20480;      // int[286] valid (l,m,n)
constexpr int OFF_VTAB2 = OFF_VTAB  + 286;        // int[146] half-set, l desc
constexpr int OFF_ZMAP  = OFF_VTAB2 + 146;        // int[396] z2 dense rebuild map
constexpr int OFF_WI1T  = OFF_ZMAP  + 408;        // W_INV1 repack [20][10 mrow][19 ni][16 l-pad]

#define DPI 3.14159265358979323846

// ---------------------------------------------------------------------------
__device__ __forceinline__ double dpowi(double x, int n) {
    double r = 1.0;
    for (int i = 0; i < n; ++i) r *= x;
    return r;
}
// F = shared factorial table F[n] = n! (bit-identical to the former dfact loop)
__device__ double wig_d(const double* F, int l, int mi, int ni, double beta) {
    int m = mi - l, n = ni - l;
    double cb = cos(0.5 * beta), sb = sin(0.5 * beta);
    double pref = sqrt(F[l + m] * F[l - m] * F[l + n] * F[l - n]);
    int s0 = (n - m) > 0 ? (n - m) : 0;
    int s1 = (l + n) < (l - m) ? (l + n) : (l - m);
    double v = 0.0;
    for (int s = s0; s <= s1; ++s) {
        double term = dpowi(cb, 2 * l + n - m - 2 * s) * dpowi(sb, m - n + 2 * s) /
                      (F[l + n - s] * F[s] * F[m - n + s] * F[l - m - s]);
        v += ((m - n + s) & 1) ? -term : term;
    }
    return pref * v;
}
__device__ double wig_pad(const double* F, int l, int m, int n, int c, double beta) {
    if (m < c - l || m > c + l || n < c - l || n > c + l) return 0.0;
    return wig_d(F, l, m - (c - l), n - (c - l), beta);
}
__device__ double quad_w(int b, int k) {
    double beta = DPI * (2 * k + 1) / (4.0 * b);
    double s = 0.0;
    for (int j = 0; j < b; ++j) s += sin((2 * j + 1) * beta) / (double)(2 * j + 1);
    return 2.0 / b * sin(beta) * s;
}

// element ids total = 212378 (unread entries skipped)
__global__ __launch_bounds__(256) void build_tables_kernel(float* ws) {
    __shared__ double sfact[21];
    if (threadIdx.x == 0) {
        double f = 1.0;
        sfact[0] = 1.0;
        for (int i = 1; i <= 20; ++i) { f *= (double)i; sfact[i] = f; }
    }
    __syncthreads();
    const double* F = sfact;

    int idx = blockIdx.x * 256 + threadIdx.x;
    if (idx < 5700) {
        int k = idx / 190, r = idx % 190, l = r / 19, m = r % 19;
        double beta = DPI * (2 * k + 1) / 60.0;
        ws[OFF_WS2 + idx] = (float)(quad_w(15, k) * wig_pad(F, l, m, 9, 9, beta));
        return;
    }
    idx -= 5700;
    if (idx < 72200) {
        // WI1T [k][mrow][ni][l] l-contiguous, pad 16; all l in [0,10) written
        if (idx >= 38000) return;
        int l = idx % 10, r = idx / 10;
        int ni = r % 19, r2 = r / 19;
        int mrow = r2 % 10, k = r2 / 10;
        double beta = DPI * (2 * k + 1) / 40.0;
        ws[OFF_WI1T + ((k * 10 + mrow) * 19 + ni) * 16 + l] =
            (float)((2 * l + 1) * wig_pad(F, l, mrow + 9, ni, 9, beta));
        return;
    }
    idx -= 72200;
    if (idx < 14520) {
        // WS3T [fidx][k] k-contiguous (stage1 phase (e) reads 20 k per fidx)
        int k = idx % 20, fidx = idx / 20;
        int l = fidx / 121, m = (fidx % 121) / 11, n = fidx % 11;
        double beta = DPI * (2 * k + 1) / 40.0;
        ws[OFF_WSO3 + fidx * 20 + k] =
            (float)(quad_w(10, k) * wig_pad(F, l, m, n, 5, beta));
        return;
    }
    idx -= 14520;
    if (idx < 8712) {
        // WI2T [k2][mrow(m-5)][n][l] l-contiguous, pad 8; l>=6 pad = 0
        if (idx >= 6336) return;
        int l = idx & 7, r = idx >> 3;
        int n = r % 11, r2 = r / 11;
        int mrow = r2 % 6, k2 = r2 / 6;
        double beta = DPI * (2 * k2 + 1) / 24.0;
        float v = 0.f;
        if (l < 6) v = (float)((2 * l + 1) * wig_pad(F, l, mrow + 5, n, 5, beta));
        ws[OFF_WINV2 + ((k2 * 6 + mrow) * 11 + n) * 8 + l] = v;
        return;
    }
    idx -= 8712;
    if (idx < 12) { ws[OFF_WINT + idx] = (float)quad_w(6, idx); return; }
    idx -= 12;
    if (idx < 570) {
        int m = idx / 30, t = idx % 30;
        double ang = -2.0 * DPI * (double)((m - 9) * t) / 30.0;
        ws[OFF_FE1 + 2 * idx] = (float)cos(ang);
        ws[OFF_FE1 + 2 * idx + 1] = (float)sin(ang);
        return;
    }
    idx -= 570;
    if (idx < 380) {
        int m = idx / 20, a = idx % 20;
        double ang = 2.0 * DPI * (double)((m - 9) * a) / 20.0;
        ws[OFF_EA1 + 2 * idx] = (float)cos(ang);
        ws[OFF_EA1 + 2 * idx + 1] = (float)sin(ang);
        return;
    }
    idx -= 380;
    if (idx < 220) {
        int m = idx / 20, a = idx % 20;
        double ang = -2.0 * DPI * (double)((m - 5) * a) / 20.0;
        ws[OFF_FF2 + 2 * idx] = (float)cos(ang);
        ws[OFF_FF2 + 2 * idx + 1] = (float)sin(ang);
        return;
    }
    idx -= 220;
    if (idx < 132) {
        int m = idx / 12, a = idx % 12;
        double ang = 2.0 * DPI * (double)((m - 5) * a) / 12.0;
        ws[OFF_EA2 + 2 * idx] = (float)cos(ang);
        ws[OFF_EA2 + 2 * idx + 1] = (float)sin(ang);
        return;
    }
    idx -= 132;
    if (idx < 4560) {
        int p = idx / 190, r = idx % 190, l = r / 19, m = r % 19;
        int bi = p / 8, ai = p % 8;
        double beta = (bi + 1) * (DPI / 24.0);
        double alpha = 2.0 * DPI * ai / 8.0;
        double re = 0.0, im = 0.0;
        if (m - 9 >= -l && m - 9 <= l) {
            double d = wig_d(F, l, m - 9 + l, l, beta);
            double ang = -(double)(m - 9) * alpha;
            re = d * cos(ang); im = d * sin(ang);
        }
        ws[OFF_BS2 + 2 * idx] = (float)re;
        ws[OFF_BS2 + 2 * idx + 1] = (float)im;
        return;
    }
    idx -= 4560;
    if (idx < 104544) {
        int p = idx / 726, r = idx % 726, l = r / 121, m = (r % 121) / 11, n = r % 11;
        int dm = m - 5, dn = n - 5;
        int am = dm < 0 ? -dm : dm, an = dn < 0 ? -dn : dn;
        if (am > l || an > l) return;                       // structurally zero
        if (!((dm > 0) || (dm == 0 && dn >= 0))) return;    // psi2 reads half-set only
        int bi = p / 48, ai = (p % 48) / 6, gi = p % 6;
        double beta = (bi + 1) * (DPI / 24.0);
        double alpha = 2.0 * DPI * ai / 8.0;
        double gamma = 2.0 * DPI * gi / 6.0;
        double d = wig_d(F, l, m - 5 + l, n - 5 + l, beta);
        double ang = -((double)(m - 5) * alpha + (double)(n - 5) * gamma);
        ws[OFF_BSO3 + 2 * idx] = (float)(d * cos(ang));
        ws[OFF_BSO3 + 2 * idx + 1] = (float)(d * sin(ang));
        return;
    }
    idx -= 104544;
    if (idx < 286) {
        int l = 0, cum = 0;
        while (idx >= cum + (2 * l + 1) * (2 * l + 1)) { cum += (2 * l + 1) * (2 * l + 1); ++l; }
        int rem = idx - cum, w = 2 * l + 1;
        int m = 5 - l + rem / w, n = 5 - l + rem % w;
        ((int*)(ws + OFF_VTAB))[idx] = l | (m << 4) | (n << 8);
        return;
    }
    idx -= 286;
    if (idx < 146) {
        int l = 5, st = 0;
        while (idx >= st + (2 * l * l + 2 * l + 1)) { st += 2 * l * l + 2 * l + 1; --l; }
        int rem = idx - st;
        int dm, dn;
        if (rem < l + 1) { dm = 0; dn = rem; }
        else { int r2 = rem - (l + 1); dm = 1 + r2 / (2 * l + 1); dn = r2 % (2 * l + 1) - l; }
        ((int*)(ws + OFF_VTAB2))[idx] = l | ((dm + 5) << 4) | ((dn + 5) << 8);
        return;
    }
    idx -= 146;
    if (idx < 396) {
        // dense z2 rebuild map: idx = ll*66 + dm*11 + n  ->  h | conj<<8 | neg<<9, -1 if zero
        int ll = idx / 66, rr = idx - ll * 66, dm = rr / 11, n = rr - dm * 11;
        int dn = n - 5, an = dn < 0 ? -dn : dn;
        int zv = -1;
        if (dm <= ll && an <= ll) {
            bool inhalf = (dm > 0) || (dm == 0 && dn >= 0);
            int ddm = inhalf ? dm : -dm, ddn = inhalf ? dn : -dn;
            int lp = ll + 1;
            int st = 146 - lp * (2 * lp * lp + 1) / 3;
            int h = st + (ddm == 0 ? ddn : (ll + 1) + (ddm - 1) * (2 * ll + 1) + (ddn + ll));
            zv = h;
            if (!inhalf) zv |= 256 | ((((dm + an) & 1) ? 1 : 0) << 9);
        }
        ((int*)(ws + OFF_ZMAP))[idx] = zv;
        return;
    }
}

// ---------------------------------------------------------------------------
// prep_kernel: psi2 (blocks 0..456) + xform1 (457..584) + psi1 (585..599)
// ---------------------------------------------------------------------------
__global__ __launch_bounds__(256) void prep_kernel(float* ws,
                                                   const float* __restrict__ k1,
                                                   const float* __restrict__ k2,
                                                   const float* __restrict__ x) {
    const int bid = blockIdx.x, tid = threadIdx.x;
    __shared__ float xs[900];
    __shared__ float2 xm[570];

    if (bid < 457) {
        int idx = bid * 256 + tid;
        if (idx >= 116800) return;
        int i = idx / 5840, r = idx % 5840, o = r / 146, h = r % 146;
        int w = ((const int*)(ws + OFF_VTAB2))[h];
        int l = w & 15, dm = ((w >> 4) & 15) - 5, dn = ((w >> 8) & 15) - 5;
        int lmn = l * 121 + (dm + 5) * 11 + (dn + 5);
        const float2* BS = (const float2*)(ws + OFF_BSO3);
        float2 s = {0.f, 0.f};
        for (int p = 0; p < 144; ++p) {
            float wv = k2[(i * 40 + o) * 144 + p];
            float2 bv = BS[p * 726 + lmn];
            s.x += wv * bv.x; s.y += wv * bv.y;
        }
        float2* row = (float2*)(ws + OFF_PSI2P) + (i * 40 + o) * 286;
        int base = l * (4 * l * l - 1) / 3, span = 2 * l + 1;
        row[base + (dm + l) * span + (dn + l)] = s;
        float sign = ((dm + dn + 16) & 1) ? -1.f : 1.f;
        row[base + (-dm + l) * span + (-dn + l)] = make_float2(sign * s.x, -sign * s.y);
        return;
    }
    if (bid < 585) {
        const int b = bid - 457;
        const float2* FE1 = (const float2*)(ws + OFF_FE1);
        const float* WS2 = ws + OFF_WS2;
        float2* Xg = (float2*)(ws + OFF_X) + b * 190;
        for (int i = tid; i < 900; i += 256) xs[i] = x[b * 900 + i];
        __syncthreads();
        for (int i = tid; i < 570; i += 256) {
            int k = i / 19, m = i % 19;
            float2 s = {0.f, 0.f};
            #pragma unroll
            for (int t = 0; t < 30; ++t) {
                float v = xs[k * 30 + t];
                float2 e = FE1[m * 30 + t];
                s.x += v * e.x; s.y += v * e.y;
            }
            xm[k * 19 + m] = s;
        }
        __syncthreads();
        for (int i = tid; i < 190; i += 256) {
            int l = i / 19, m = i % 19;
            float2 s = {0.f, 0.f};
            for (int k = 0; k < 30; ++k) {
                float w = WS2[k * 190 + l * 19 + m];
                float2 v = xm[k * 19 + m];
                s.x += w * v.x; s.y += w * v.y;
            }
            Xg[i] = s;
        }
        return;
    }
    {
        int idx = (bid - 585) * 256 + tid;
        if (idx >= 3800) return;
        int o = idx / 190, r = idx % 190;
        const float2* BS2 = (const float2*)(ws + OFF_BS2);
        float2 s = {0.f, 0.f};
        for (int p = 0; p < 24; ++p) {
            float w = k1[o * 24 + p];
            float2 bv = BS2[p * 190 + r];
            s.x += w * bv.x; s.y += w * bv.y;
        }
        ((float2*)(ws + OFF_PSI))[idx] = s;
    }
}

// ---------------------------------------------------------------------------
// stage1 v18 = v17 + phase (e) WS3T k-contiguous: 20 k-strided gathers ->
// 5x dwordx4 (rows are 80B, 16B-aligned). Same values, same k-order ->
// bit-identical.
// ---------------------------------------------------------------------------
__global__ __launch_bounds__(256, 4) void stage1_kernel(
    const float* __restrict__ WI1T, const float* __restrict__ WS3T,
    const float* __restrict__ EA1, const float* __restrict__ FF2,
    const float2* __restrict__ Xall, const float2* __restrict__ Pall,
    const int* __restrict__ VTAB, float2* __restrict__ X2out)
{
    const int tid = threadIdx.x;
    const int wv = tid >> 6, lane = tid & 63;
    const int b = blockIdx.x / 20;
    const int o = blockIdx.x % 20;
    const float2* Xg = Xall + b * 190;
    const float2* Pg = Pall + o * 190;
    float2* X2g = X2out + (b * 20 + o) * 286;
    const float2* EA1c = (const float2*)EA1;
    const float2* FF2c = (const float2*)FF2;

    __shared__ float2 Xs[100];         // [l][mrow] = X[l][mrow+9], dense
    __shared__ float2 Ps[190];         // [l][ni], dense
    __shared__ float2 fhA[3800];       // [20 k][190]; uu aliases [950w,950w+600),
                                       // ymn rows k at [950*(k/5)+600+(k%5)*66, +66)

    const int kl = lane / 10;          // local k within wave (active: kl < 5)
    const int gpair = lane % 10;
    const bool active = (lane < 50);

    float2 eg[19];
    #pragma unroll
    for (int n = 0; n < 19; ++n) eg[n] = EA1c[n * 20 + gpair];

    // wave-redundant staging (identical values -> benign WW race, no barrier)
    for (int i = lane; i < 100; i += 64) Xs[i] = Xg[(i / 10) * 19 + 9 + (i % 10)];
    for (int i = lane; i < 190; i += 64) Ps[i] = Pg[i];

    // (a) wave-local: build own 5 fh rows (950 items), uniform l=0..9
    float2* fhW = fhA + 950 * wv;
    for (int i = lane; i < 950; i += 64) {
        int klq = i / 190, idx = i - klq * 190;
        int k = 5 * wv + klq;
        int mrow = idx / 19, ni = idx - mrow * 19;
        const float* wt = WI1T + ((k * 10 + mrow) * 19 + ni) * 16;
        float4 wa = *(const float4*)(wt);
        float4 wb = *(const float4*)(wt + 4);
        float2 wc = *(const float2*)(wt + 8);
        float wl_[10] = {wa.x, wa.y, wa.z, wa.w, wb.x, wb.y, wb.z, wb.w, wc.x, wc.y};
        float2 s = {0.f, 0.f};
        #pragma unroll
        for (int l = 0; l < 10; ++l) {
            float2 a = Xs[l * 10 + mrow], c = Ps[l * 19 + ni];
            float wvv = wl_[l];
            s.x += wvv * (a.x * c.x + a.y * c.y);
            s.y += wvv * (a.y * c.x - a.x * c.y);
        }
        fhW[i] = s;
    }

    // (b) wave-local per-lane column-PAIR pipeline (reads own rows only)
    float2 uacc0[6], uacc1[6];
    if (active) {
        const float2* fhk = fhW + kl * 190;
        float ye0[10], yo0[10], ye1[10], yo1[10];
        {
            float2 te = {0.f, 0.f}, to = {0.f, 0.f};
            #pragma unroll
            for (int n = 0; n < 19; ++n) {
                float2 f = fhk[n];
                float rx = f.x * eg[n].x - f.y * eg[n].y;
                float ry = f.x * eg[n].y + f.y * eg[n].x;
                if (n & 1) { te.x += rx; te.y += ry; }
                else       { to.x += rx; to.y += ry; }
            }
            float t0x = te.x + to.x, t1x = te.x - to.x;
            #pragma unroll
            for (int a = 0; a < 10; ++a) {
                ye0[a] = t0x; yo0[a] = 0.f;
                ye1[a] = t1x; yo1[a] = 0.f;
            }
        }
        #pragma unroll 1   // r7 lesson: full unroll -> VGPR cliff
        for (int mrow = 1; mrow < 10; ++mrow) {
            float2 te = {0.f, 0.f}, to = {0.f, 0.f};
            #pragma unroll
            for (int n = 0; n < 19; ++n) {
                float2 f = fhk[mrow * 19 + n];
                float rx = f.x * eg[n].x - f.y * eg[n].y;
                float ry = f.x * eg[n].y + f.y * eg[n].x;
                if (n & 1) { te.x += rx; te.y += ry; }
                else       { to.x += rx; to.y += ry; }
            }
            float2 t0 = make_float2(2.f * (te.x + to.x), 2.f * (te.y + to.y));
            float2 t1 = make_float2(2.f * (te.x - to.x), 2.f * (te.y - to.y));
            if (mrow & 1) {
                #pragma unroll
                for (int a = 0; a < 10; ++a) {
                    float2 e = EA1c[(9 + mrow) * 20 + a];
                    yo0[a] += t0.x * e.x - t0.y * e.y;
                    yo1[a] += t1.x * e.x - t1.y * e.y;
                }
            } else {
                #pragma unroll
                for (int a = 0; a < 10; ++a) {
                    float2 e = EA1c[(9 + mrow) * 20 + a];
                    ye0[a] += t0.x * e.x - t0.y * e.y;
                    ye1[a] += t1.x * e.x - t1.y * e.y;
                }
            }
        }
        #pragma unroll
        for (int a = 0; a < 10; ++a) {
            float p0 = ye0[a] + yo0[a]; p0 = p0 > 0.f ? p0 : 0.f;
            float q0 = ye0[a] - yo0[a]; q0 = q0 > 0.f ? q0 : 0.f;
            ye0[a] = p0 + q0; yo0[a] = p0 - q0;
            float p1 = ye1[a] + yo1[a]; p1 = p1 > 0.f ? p1 : 0.f;
            float q1 = ye1[a] - yo1[a]; q1 = q1 > 0.f ? q1 : 0.f;
            ye1[a] = p1 + q1; yo1[a] = p1 - q1;
        }
        uacc0[0] = make_float2(0.f, 0.f); uacc1[0] = make_float2(0.f, 0.f);
        #pragma unroll
        for (int a = 0; a < 10; ++a) { uacc0[0].x += ye0[a]; uacc1[0].x += ye1[a]; }
        #pragma unroll
        for (int d = 1; d < 6; ++d) {
            uacc0[d] = make_float2(0.f, 0.f); uacc1[d] = make_float2(0.f, 0.f);
            #pragma unroll
            for (int a = 0; a < 10; ++a) {
                float q0 = (d & 1) ? yo0[a] : ye0[a];
                float q1 = (d & 1) ? yo1[a] : ye1[a];
                float2 e = FF2c[(5 + d) * 20 + a];
                uacc0[d].x += e.x * q0; uacc0[d].y += e.y * q0;
                uacc1[d].x += e.x * q1; uacc1[d].y += e.y * q1;
            }
        }
    }

    // (c) wave-local uu write into own (already-consumed) region
    if (active) {
        float2* uu = fhW + kl * 120;
        #pragma unroll
        for (int d = 0; d < 6; ++d) {
            uu[d * 20 + gpair]      = uacc0[d];
            uu[d * 20 + gpair + 10] = uacc1[d];
        }
    }
    __syncthreads();   // barrier #1: all waves' uu visible

    // (d) block-wide: ymn rows mi=5..10, g-FOLDED; writes into per-wave gaps
    for (int i = tid; i < 1320; i += 256) {
        int k = i / 66, rr = i - k * 66;
        int d = rr / 11, ni = rr - d * 11;
        const float2* uurow = fhA + 950 * (k / 5) + (k % 5) * 120 + d * 20;
        float sgn = (ni & 1) ? 1.f : -1.f;
        float2 s = {0.f, 0.f};
        #pragma unroll
        for (int gg = 0; gg < 10; ++gg) {
            float2 ua = uurow[gg], ub = uurow[gg + 10];
            float ux = ua.x + sgn * ub.x, uy = ua.y + sgn * ub.y;
            float2 e = FF2c[ni * 20 + gg];
            s.x += ux * e.x - uy * e.y;
            s.y += ux * e.y + uy * e.x;
        }
        fhA[950 * (k / 5) + 600 + (k % 5) * 66 + rr] = s;
    }
    __syncthreads();   // barrier #2: ymn visible

    // (e) per-lane acc over all 20 k + packed write (WS3T k-contiguous)
    for (int v = tid; v < 286; v += 256) {
        int w = VTAB[v];
        int l = w & 15, m = (w >> 4) & 15, n = (w >> 8) & 15;
        int fidx = l * 121 + m * 11 + n;
        int off; float sy;
        if (m >= 5) { off = (m - 5) * 11 + n; sy = 1.f; }
        else        { off = (5 - m) * 11 + (10 - n); sy = -1.f; }
        const float* wt = WS3T + fidx * 20;
        float4 w0 = *(const float4*)(wt);
        float4 w1 = *(const float4*)(wt + 4);
        float4 w2 = *(const float4*)(wt + 8);
        float4 w3 = *(const float4*)(wt + 12);
        float4 w4 = *(const float4*)(wt + 16);
        float wl_[20] = {w0.x, w0.y, w0.z, w0.w, w1.x, w1.y, w1.z, w1.w,
                         w2.x, w2.y, w2.z, w2.w, w3.x, w3.y, w3.z, w3.w,
                         w4.x, w4.y, w4.z, w4.w};
        float2 s = {0.f, 0.f};
        #pragma unroll
        for (int k = 0; k < 20; ++k) {
            float2 ym = fhA[950 * (k / 5) + 600 + (k % 5) * 66 + off];
            s.x += wl_[k] * ym.x;
            s.y += wl_[k] * sy * ym.y;
        }
        X2g[v] = s;
    }
}

// ---------------------------------------------------------------------------
// stage2 v16 = v15 + EA2 staged in LDS (per-lane g/a reads in t2/final are
// vector GATHERS, not uniform s_loads -> r8's lesson doesn't apply; ds_read
// drops the 64-bit addressing + VMEM latency). Wave-redundant copy, no
// barrier. Arithmetic unchanged -> bit-identical.
// ---------------------------------------------------------------------------
__global__ __launch_bounds__(256) void stage2_kernel(float* ws) {
    const int tid = threadIdx.x;
    const int wave = tid >> 6, lane = tid & 63;
    // XCD-aware bijective remap: blockIdx round-robins XCDs; give each XCD a
    // contiguous chunk of (bp,og) space so same-bp blocks share an L2.
    const int wg = (blockIdx.x & 7) * 160 + (blockIdx.x >> 3);
    const int bp = wg / 20;                    // b-pair 0..63
    const int og = wg % 20;                    // o-pair 0..19
    const int b0 = bp * 2, o0 = og * 2;
    const int bsel = wave >> 1, osel = wave & 1;   // wave w -> (b0+bsel, o0+osel)

    const float*  WI2T = ws + OFF_WINV2;   // [k2][mrow][n][8 l-pad]
    const float2* EA2 = (const float2*)(ws + OFF_EA2);
    const float*  WIT = ws + OFF_WINT;
    const int*  VTAB2 = (const int*)(ws + OFF_VTAB2);
    const int*   ZMAP = (const int*)(ws + OFF_ZMAP);
    const float4* WS4 = (const float4*)ws;
    float* featp = ws + OFF_FEAT;

    // LDS (floats): [0,1168) P partials [4 pair][146] f2 (live past phase A)
    //   [1168,5808): staging dbuf, 2 x 2320 f (4 arrays @ f2 0/286/572/858,
    //                pad f2 1144..1160 for masked unroll reads)
    //   B/C alias: z2a [1168,1960) 396 f2 ; z2b [1960,2752) 396 f2
    //              fh2 [2752,4336) 792 f2 ; t2 [4336,6064) 864 f2
    __shared__ __align__(16) float sm[6064];
    __shared__ float2 EA2s[132];

    // wave-redundant EA2 copy (reads are same-wave, lgkmcnt-ordered)
    for (int i = lane; i < 132; i += 64) EA2s[i] = EA2[i];

    // per-lane entry setup (same half-set per wave; wave's own (b,o) pair)
    int xo[3], po[3], klen[3];
    float2 acc[3];
    #pragma unroll
    for (int t = 0; t < 3; ++t) {
        int v = lane + 64 * t;
        acc[t] = make_float2(0.f, 0.f);
        if (v < 146) {
            int w = VTAB2[v];
            int l = w & 15, dm = ((w >> 4) & 15) - 5, dn = ((w >> 8) & 15) - 5;
            int base = l * (4 * l * l - 1) / 3, span = 2 * l + 1;
            xo[t] = base + (dm + l) * span;
            po[t] = base + (dn + l) * span;
            klen[t] = span;
        } else { xo[t] = 0; po[t] = 0; klen[t] = 0; }
    }

    // staging source setup: arrays [xi(b0), xi(b0+1), pp(o0), pp(o0+1)],
    // each 143 float4; 572 f4 per tile. Slices 0/1: v = tid, tid+256.
    // Slice 2 (60 items): v = 512 + wave*15 + lane, lane<15 — balanced.
    int fb[3], fstep[3];
    #pragma unroll
    for (int j = 0; j < 2; ++j) {
        int v = tid + 256 * j;
        int arr = v / 143, idxq = v - arr * 143;
        if (arr < 2) { fb[j] = (OFF_X2P >> 2) + (b0 + arr) * 20 * 143 + idxq; fstep[j] = 143; }
        else         { fb[j] = (OFF_PSI2P >> 2) + (o0 + arr - 2) * 143 + idxq; fstep[j] = 5720; }
    }
    int e3 = wave * 15 + lane; if (e3 > 59) e3 = 59;
    const int v3 = 512 + e3;                 // in [512,571] -> arr==3 always
    fb[2] = (OFF_PSI2P >> 2) + (o0 + 1) * 143 + (v3 - 429);
    fstep[2] = 5720;
    const bool f2ok = (lane < 15);

    constexpr int KMAX0 = 11, KMAX1 = 9, KMAX2 = 5;   // static slot max klen
    auto computeTile = [&](const float* smbase) {
        const float2* bufF2 = (const float2*)smbase;
        const float2* xiW = bufF2 + bsel * 286;
        const float2* ppW = bufF2 + (2 + osel) * 286;
        {
            const float2* xp = xiW + xo[0];
            const float2* pq = ppW + po[0];
            const int kl = klen[0];
            #pragma unroll
            for (int k = 0; k < KMAX0; ++k) {
                float2 u = xp[k], v2 = pq[k];
                if (k < kl) {
                    acc[0].x += u.x * v2.x + u.y * v2.y;
                    acc[0].y += u.y * v2.x - u.x * v2.y;
                }
            }
        }
        {
            const float2* xp = xiW + xo[1];
            const float2* pq = ppW + po[1];
            const int kl = klen[1];
            #pragma unroll
            for (int k = 0; k < KMAX1; ++k) {
                float2 u = xp[k], v2 = pq[k];
                if (k < kl) {
                    acc[1].x += u.x * v2.x + u.y * v2.y;
                    acc[1].y += u.y * v2.x - u.x * v2.y;
                }
            }
        }
        {
            const float2* xp = xiW + xo[2];
            const float2* pq = ppW + po[2];
            const int kl = klen[2];
            #pragma unroll
            for (int k = 0; k < KMAX2; ++k) {
                float2 u = xp[k], v2 = pq[k];
                if (k < kl) {
                    acc[2].x += u.x * v2.x + u.y * v2.y;
                    acc[2].y += u.y * v2.x - u.x * v2.y;
                }
            }
        }
    };

    // prefetch tiles 0 (set A) and 1 (set B)
    float4 rgA0 = WS4[fb[0]], rgA1 = WS4[fb[1]];
    float4 rgA2; if (f2ok) rgA2 = WS4[fb[2]];
    fb[0] += fstep[0]; fb[1] += fstep[1]; fb[2] += fstep[2];
    float4 rgB0 = WS4[fb[0]], rgB1 = WS4[fb[1]];
    float4 rgB2; if (f2ok) rgB2 = WS4[fb[2]];

    // phase A: unroll-by-2, 1 barrier/half-iter, loads issued 2 tiles ahead
    for (int i = 0; i < 20; i += 2) {
        float4* A4 = (float4*)(sm + 1168);
        A4[tid]       = rgA0;
        A4[tid + 256] = rgA1;
        if (f2ok) A4[v3] = rgA2;
        __syncthreads();
        if (i + 2 < 20) {
            fb[0] += fstep[0]; fb[1] += fstep[1]; fb[2] += fstep[2];
            rgA0 = WS4[fb[0]]; rgA1 = WS4[fb[1]];
            if (f2ok) rgA2 = WS4[fb[2]];
        }
        computeTile(sm + 1168);

        float4* B4 = (float4*)(sm + 1168 + 2320);
        B4[tid]       = rgB0;
        B4[tid + 256] = rgB1;
        if (f2ok) B4[v3] = rgB2;
        __syncthreads();
        if (i + 3 < 20) {
            fb[0] += fstep[0]; fb[1] += fstep[1]; fb[2] += fstep[2];
            rgB0 = WS4[fb[0]]; rgB1 = WS4[fb[1]];
            if (f2ok) rgB2 = WS4[fb[2]];
        }
        computeTile(sm + 1168 + 2320);
    }

    // write complete per-pair partials (P region disjoint from staging)
    float2* P = (float2*)sm;   // [4 pair][146]
    #pragma unroll
    for (int t = 0; t < 3; ++t) {
        int v = lane + 64 * t;
        if (v < 146) P[wave * 146 + v] = acc[t];
    }
    __syncthreads();

    // phases B/C per pair p: (b0 + (p>>1), o0 + (p&1)); z2 double-buffered,
    // z2(p+1) built between fh2(p) and t2(p) -> one barrier per pair.
    float2* z2A = (float2*)(sm + 1168);   // [6 l][6 m>=5][11 n]
    float2* z2B = (float2*)(sm + 1960);
    float2* fh2 = (float2*)(sm + 2752);   // [12 k2][6 m][11 n]
    float2* t2  = (float2*)(sm + 4336);   // [12 k2][6 d][12 g]

    // prologue: build z2 for p=0
    for (int idx = tid; idx < 396; idx += 256) {
        int zv = ZMAP[idx];
        float2 s = {0.f, 0.f};
        if (zv >= 0) {
            s = P[(zv & 255)];
            if (zv & 256) {
                float sg = (zv & 512) ? -1.f : 1.f;
                s = make_float2(sg * s.x, -sg * s.y);
            }
        }
        z2A[idx] = s;
    }
    __syncthreads();

    for (int p = 0; p < 4; ++p) {
        const float2* zin  = (p & 1) ? z2B : z2A;
        float2*       zout = (p & 1) ? z2A : z2B;
        // C: fh2 rows for own k2 = 3w..3w+2 (198 items/wave), uniform ll=0..5
        for (int li = lane; li < 198; li += 64) {
            int k2 = wave * 3 + li / 66;
            int rr = li % 66;
            const float* wt = WI2T + (k2 * 66 + rr) * 8;
            float4 wa = *(const float4*)(wt);
            float2 wb = *(const float2*)(wt + 4);
            float wl_[6] = {wa.x, wa.y, wa.z, wa.w, wb.x, wb.y};
            float2 s = {0.f, 0.f};
            #pragma unroll
            for (int ll = 0; ll < 6; ++ll) {
                float2 z = zin[ll * 66 + rr];
                s.x += wl_[ll] * z.x; s.y += wl_[ll] * z.y;
            }
            fh2[k2 * 66 + rr] = s;
        }
        asm volatile("s_waitcnt lgkmcnt(0)" ::: "memory");   // wave-local fh2 ready
        // pipeline: build z2 for next pair into the other buffer (block-wide;
        // completion guaranteed by the end-of-pair barrier)
        if (p < 3) {
            for (int idx = tid; idx < 396; idx += 256) {
                int zv = ZMAP[idx];
                float2 s = {0.f, 0.f};
                if (zv >= 0) {
                    s = P[(p + 1) * 146 + (zv & 255)];
                    if (zv & 256) {
                        float sg = (zv & 512) ? -1.f : 1.f;
                        s = make_float2(sg * s.x, -sg * s.y);
                    }
                }
                zout[idx] = s;
            }
        }
        // t2: per-wave own k2 (216 items/wave)
        for (int li = lane; li < 216; li += 64) {
            int k2 = wave * 3 + li / 72;
            int rr = li % 72, mrow = rr / 12, g = rr - mrow * 12;
            float2 s = {0.f, 0.f};
            #pragma unroll
            for (int n = 0; n < 11; ++n) {
                float2 f = fh2[k2 * 66 + mrow * 11 + n], e = EA2s[n * 12 + g];
                s.x += f.x * e.x - f.y * e.y;
                s.y += f.x * e.y + f.y * e.x;
            }
            t2[k2 * 72 + rr] = s;
        }
        asm volatile("s_waitcnt lgkmcnt(0)" ::: "memory");   // wave-local t2 ready
        // final: per-wave own k2 (216 items/wave), relu + quad-weight acc
        float partial = 0.f;
        for (int li = lane; li < 216; li += 64) {
            int k2 = wave * 3 + li / 72;
            int rr = li % 72, a = rr / 12, g = rr - a * 12;
            float base = t2[k2 * 72 + g].x;
            float se = 0.f, so = 0.f;
            #pragma unroll
            for (int d = 1; d < 6; ++d) {
                float2 e = EA2s[(5 + d) * 12 + a];
                float2 t = t2[k2 * 72 + d * 12 + g];
                float c = 2.f * (e.x * t.x - e.y * t.y);
                if (d & 1) so += c; else se += c;
            }
            float y0 = base + se + so, y1 = base + se - so;
            float w = WIT[k2];
            if (y0 > 0.f) partial += w * y0;
            if (y1 > 0.f) partial += w * y1;
        }
        for (int off = 32; off > 0; off >>= 1) partial += __shfl_down(partial, off, 64);
        if (lane == 0)
            featp[((b0 + (p >> 1)) * 40 + o0 + (p & 1)) * 4 + wave] = partial;
        __syncthreads();   // z2(p+1) complete; safe to reuse buffers next pair
    }
}

// ---------------------------------------------------------------------------
__global__ __launch_bounds__(256) void final_kernel(const float* __restrict__ ws,
                                                    const float* __restrict__ wl,
                                                    const float* __restrict__ bl,
                                                    float* __restrict__ out) {
    int idx = blockIdx.x * 256 + threadIdx.x;
    if (idx >= 1280) return;
    int b = idx / 10, f = idx % 10;
    const float* fp = ws + OFF_FEAT;
    float s = bl[f];
    for (int o = 0; o < 40; ++o) {
        const float* q = fp + (b * 40 + o) * 4;
        s += ((q[0] + q[1] + q[2] + q[3]) * (1.0f / 144.0f)) * wl[f * 40 + o];
    }
    out[idx] = s;
}

// ---------------------------------------------------------------------------
extern "C" void kernel_launch(void* const* d_in, const int* in_sizes, int n_in,
                              void* d_out, int out_size, void* d_ws, size_t ws_size,
                              hipStream_t stream) {
    (void)in_sizes; (void)n_in; (void)out_size; (void)ws_size;
    const float* x  = (const float*)d_in[0];
    const float* k1 = (const float*)d_in[1];
    const float* k2 = (const float*)d_in[2];
    const float* wl = (const float*)d_in[3];
    const float* bl = (const float*)d_in[4];
    float* out = (float*)d_out;
    float* ws  = (float*)d_ws;

    build_tables_kernel<<<830, 256, 0, stream>>>(ws);
    prep_kernel<<<600, 256, 0, stream>>>(ws, k1, k2, x);
    stage1_kernel<<<128 * 20, 256, 0, stream>>>(
        ws + OFF_WI1T, ws + OFF_WSO3, ws + OFF_EA1, ws + OFF_FF2,
        (const float2*)(ws + OFF_X), (const float2*)(ws + OFF_PSI),
        (const int*)(ws + OFF_VTAB), (float2*)(ws + OFF_X2P));
    stage2_kernel<<<128 * 10, 256, 0, stream>>>(ws);
    final_kernel<<<5, 256, 0, stream>>>(ws, wl, bl, out);
}